// Round 8
// baseline (480.701 us; speedup 1.0000x reference)
//
#include <hip/hip_runtime.h>
#include <hip/hip_bf16.h>

// GCN 2-layer. CSR via block-local radix partition, 16-padded lists (dummy node N).
// h' = isd*(x@W1) stored GROUP-MAJOR: Hg[g][node][16ch], g = XCD shard (blockIdx&7).
// agg1 gathers only its 3.2MB slab per XCD (L2-resident). h1 also group-major.
// h2' = isd*(h1@W2). Intermediates bf16. GEMM1 = bf16 MFMA.

#define CHUNK   4096              // edges per partition block (392 blocks)
#define NPB     512               // nodes per bucket (dst >> 9)
#define NBUCK   196               // ceil(100000/512)
#define BBCAP   9216              // bucket capacity (mean 8163, +11 sigma)

typedef __bf16 bf16x8 __attribute__((ext_vector_type(8)));
typedef float floatx4 __attribute__((ext_vector_type(4)));

__device__ inline unsigned short f2bf(float f) {      // RNE fp32->bf16
    unsigned u = __float_as_uint(f);
    u += 0x7FFF + ((u >> 16) & 1);
    return (unsigned short)(u >> 16);
}
__device__ inline float bflo(unsigned p) { return __uint_as_float(p << 16); }
__device__ inline float bfhi(unsigned p) { return __uint_as_float(p & 0xFFFF0000u); }

// ---------------- pass 1: block-local radix partition by dst>>9 ----------------
__global__ __launch_bounds__(256) void k_part(const int* __restrict__ src,
                                              const int* __restrict__ dst,
                                              int* __restrict__ gcursor,
                                              unsigned* __restrict__ buckets, int E) {
    __shared__ unsigned srec[CHUNK];          // 16 KB
    __shared__ unsigned char sb8[CHUNK];      // 4 KB
    __shared__ int hist[NBUCK];
    __shared__ int lbase[NBUCK];
    __shared__ int gbase[NBUCK];
    __shared__ int scanbuf[256];
    int t = threadIdx.x;
    int base = blockIdx.x * CHUNK;
    int cnt = min(CHUNK, E - base);           // multiple of 4
    for (int i = t; i < NBUCK; i += 256) hist[i] = 0;
    __syncthreads();

    unsigned rec[16];
    unsigned br[16];                          // b (8b) | rank<<8
    bool valid[4];
    #pragma unroll
    for (int k = 0; k < 4; ++k) {
        int e0 = k * 1024 + t * 4;
        valid[k] = (e0 < cnt);
        if (valid[k]) {
            int4 s4 = *(const int4*)&src[base + e0];
            int4 d4 = *(const int4*)&dst[base + e0];
            int ss[4] = {s4.x, s4.y, s4.z, s4.w};
            int dd[4] = {d4.x, d4.y, d4.z, d4.w};
            #pragma unroll
            for (int j = 0; j < 4; ++j) {
                int b = dd[j] >> 9;
                int r = atomicAdd(&hist[b], 1);           // LDS atomic
                rec[k * 4 + j] = (unsigned)ss[j] | ((unsigned)(dd[j] & 511) << 17);
                br[k * 4 + j] = (unsigned)b | ((unsigned)r << 8);
            }
        }
    }
    __syncthreads();
    scanbuf[t] = (t < NBUCK) ? hist[t] : 0;
    __syncthreads();
    for (int s = 1; s < 256; s <<= 1) {
        int v = (t >= s) ? scanbuf[t - s] : 0;
        __syncthreads();
        scanbuf[t] += v;
        __syncthreads();
    }
    if (t < NBUCK) {
        lbase[t] = scanbuf[t] - hist[t];
        gbase[t] = atomicAdd(&gcursor[t], hist[t]);
    }
    __syncthreads();
    #pragma unroll
    for (int k = 0; k < 4; ++k) {
        if (valid[k]) {
            #pragma unroll
            for (int j = 0; j < 4; ++j) {
                unsigned b = br[k * 4 + j] & 255u;
                unsigned r = br[k * 4 + j] >> 8;
                int p = lbase[b] + (int)r;
                srec[p] = rec[k * 4 + j];
                sb8[p] = (unsigned char)b;
            }
        }
    }
    __syncthreads();
    for (int i = t; i < cnt; i += 256) {
        int b = sb8[i];
        int pos = gbase[b] + (i - lbase[b]);
        if (pos < BBCAP) buckets[(size_t)b * BBCAP + pos] = srec[i];
    }
}

// ---------------- pass 2a: per-bucket deg histogram (dense) ----------------
__global__ __launch_bounds__(256) void k_count(const unsigned* __restrict__ buckets,
                                               const int* __restrict__ gcursor,
                                               int* __restrict__ deg, int N) {
    __shared__ int hist[NPB];
    int b = blockIdx.x;
    for (int i = threadIdx.x; i < NPB; i += 256) hist[i] = 0;
    __syncthreads();
    int cnt = min(gcursor[b], BBCAP);
    const unsigned* bk = &buckets[(size_t)b * BBCAP];
    for (int i = threadIdx.x; i < cnt; i += 256)
        atomicAdd(&hist[bk[i] >> 17], 1);
    __syncthreads();
    int node0 = b << 9;
    for (int i = threadIdx.x; i < NPB; i += 256)
        if (node0 + i < N) deg[node0 + i] = hist[i];
}

// ---------------- isd + offsets over PADDED degree ----------------
__global__ void k_isd_offsets(const int* __restrict__ deg, float* __restrict__ isd,
                              int* __restrict__ offsets, int* __restrict__ counter, int N) {
    int n = blockIdx.x * blockDim.x + threadIdx.x;
    int lane = threadIdx.x & 63;
    int d = (n < N) ? deg[n] : 0;
    if (n <= N) isd[n] = (d > 0) ? rsqrtf((float)d) : 0.f;   // isd[N]=0 dummy
    int dp = (d + 15) & ~15;
    int pref = dp;
    #pragma unroll
    for (int sh = 1; sh < 64; sh <<= 1) {
        int t = __shfl_up(pref, sh);
        if (lane >= sh) pref += t;
    }
    int total = __shfl(pref, 63);
    int base = 0;
    if (lane == 63) base = atomicAdd(counter, total);
    base = __shfl(base, 63);
    if (n < N) offsets[n] = base + pref - dp;
}

// ---------------- pass 2b: placement via LDS cursors + dummy-pad fill ----------------
__global__ __launch_bounds__(256) void k_place(const unsigned* __restrict__ buckets,
                                               const int* __restrict__ gcursor,
                                               const int* __restrict__ offsets,
                                               const int* __restrict__ deg,
                                               int* __restrict__ csr, int N) {
    __shared__ int cur[NPB];
    int b = blockIdx.x;
    int node0 = b << 9;
    for (int i = threadIdx.x; i < NPB; i += 256)
        cur[i] = (node0 + i < N) ? offsets[node0 + i] : 0;
    __syncthreads();
    int cnt = min(gcursor[b], BBCAP);
    const unsigned* bk = &buckets[(size_t)b * BBCAP];
    for (int i = threadIdx.x; i < cnt; i += 256) {
        unsigned r = bk[i];
        int p = atomicAdd(&cur[r >> 17], 1);
        csr[p] = (int)(r & 0x1FFFFu);
    }
    __syncthreads();
    for (int i = threadIdx.x; i < NPB; i += 256) {
        int n = node0 + i;
        if (n < N) {
            int d = deg[n];
            int st = offsets[n] + d;
            int en = offsets[n] + ((d + 15) & ~15);
            for (int p = st; p < en; ++p) csr[p] = N;
        }
    }
}

// ---------------- W1 -> bf16 MFMA B-fragment order; zero h2' dummy row ----------------
__global__ void k_prep_w1(const float* __restrict__ W1, unsigned short* __restrict__ w1s,
                          unsigned* __restrict__ h2z) {
    if (blockIdx.x == 0 && threadIdx.x < 36) h2z[threadIdx.x] = 0;  // row N + slack
    int flat = blockIdx.x * 256 + threadIdx.x;   // 0..4095
    int kt = flat >> 9;
    int nt = (flat >> 6) & 7;
    int lane = flat & 63;
    int kbase = kt * 32 + ((lane >> 4) << 3);
    int n = nt * 16 + (lane & 15);
    unsigned short v[8];
    #pragma unroll
    for (int j = 0; j < 8; ++j) v[j] = f2bf(W1[(size_t)(kbase + j) * 128 + n]);
    unsigned short* d = &w1s[(size_t)flat * 8];
    *(short4*)(d)     = make_short4(v[0], v[1], v[2], v[3]);
    *(short4*)(d + 4) = make_short4(v[4], v[5], v[6], v[7]);
}

// ---------------- GEMM1: Hg[g][node][16ch](bf16) = isd*(x @ W1) ----------------
__global__ __launch_bounds__(256) void k_gemm1(const float* __restrict__ X,
                                               const unsigned short* __restrict__ w1s,
                                               const float* __restrict__ isd,
                                               unsigned* __restrict__ Hg, int N) {
    __shared__ __align__(16) unsigned short smem[8192];
    unsigned short* sA = smem;
    unsigned short* sB = smem + 2048;
    int tid = threadIdx.x;
    int lane = tid & 63;
    int wave = tid >> 6;
    int wr = wave >> 1;
    int wc = wave & 1;
    int m0 = blockIdx.x * 64;

    floatx4 acc[2][4] = {};

    for (int kt = 0; kt < 8; ++kt) {
        #pragma unroll
        for (int i = 0; i < 2; ++i) {
            int f = tid * 2 + i;
            int row = f >> 3;
            int c4 = (f & 7) * 4;
            float4 v = make_float4(0.f, 0.f, 0.f, 0.f);
            int grow = m0 + row;
            if (grow < N) v = *(const float4*)&X[(size_t)grow * 256 + kt * 32 + c4];
            int mt = row >> 4;
            int flane = (row & 15) | ((c4 >> 3) << 4);
            int j0 = c4 & 7;
            unsigned short* d = &sA[(size_t)(mt * 64 + flane) * 8 + j0];
            *(short4*)d = make_short4(f2bf(v.x), f2bf(v.y), f2bf(v.z), f2bf(v.w));
        }
        {
            const float4* srcp = (const float4*)&w1s[(size_t)kt * 4096];
            float4* dstp = (float4*)sB;
            dstp[tid] = srcp[tid];
            dstp[tid + 256] = srcp[tid + 256];
        }
        __syncthreads();
        bf16x8 a[2], b[4];
        #pragma unroll
        for (int p = 0; p < 2; ++p)
            a[p] = *(const bf16x8*)&sA[(size_t)((wr * 2 + p) * 64 + lane) * 8];
        #pragma unroll
        for (int q = 0; q < 4; ++q)
            b[q] = *(const bf16x8*)&sB[(size_t)((wc * 4 + q) * 64 + lane) * 8];
        #pragma unroll
        for (int p = 0; p < 2; ++p)
            #pragma unroll
            for (int q = 0; q < 4; ++q)
                acc[p][q] = __builtin_amdgcn_mfma_f32_16x16x32_bf16(a[p], b[q], acc[p][q], 0, 0, 0);
        __syncthreads();
    }
    float sc[2][4];
    #pragma unroll
    for (int p = 0; p < 2; ++p)
        #pragma unroll
        for (int r = 0; r < 4; ++r) {
            int g = m0 + wr * 32 + p * 16 + ((lane >> 4) << 2) + r;
            sc[p][r] = isd[g > N ? N : g];
        }
    #pragma unroll
    for (int p = 0; p < 2; ++p)
        #pragma unroll
        for (int q = 0; q < 4; ++q)
            #pragma unroll
            for (int r = 0; r < 4; ++r) {
                int rl = wr * 32 + p * 16 + ((lane >> 4) << 2) + r;
                int c = wc * 64 + q * 16 + (lane & 15);
                smem[rl * 128 + c] = f2bf(acc[p][q][r] * sc[p][r]);
            }
    __syncthreads();
    // group-major epilogue: slice (g,row) = 32B = 8 uints at Hg[g][(m0+row)]
    size_t gstride = (size_t)(N + 1) * 8;     // uints per group slab
    const unsigned* sm = (const unsigned*)smem;
    #pragma unroll
    for (int i = 0; i < 2; ++i) {
        int f = tid + i * 256;                // 0..511
        int g = f & 7;
        int row = f >> 3;
        int grow = m0 + row;
        if (grow <= N) {   // row N = zeros (dummy, sc=0)
            unsigned* dstp = Hg + (size_t)g * gstride + (size_t)grow * 8;
            const unsigned* s = sm + row * 64 + g * 8;
            *(uint4*)dstp       = *(const uint4*)s;
            *(uint4*)(dstp + 4) = *(const uint4*)(s + 4);
        }
    }
}

// ---------------- agg1: H1g[g][node][16ch] = relu(b1 + isdn*sum Hg[g][src]) ----------
// XCD shard: g = blockIdx&7 -> each XCD gathers from its own 3.2MB slab.
// lane = edge_sub(0..7)*8 + chpair(0..7); 8 edges per gather instr; butterfly reduce.
__global__ __launch_bounds__(256) void k_agg1(const unsigned* __restrict__ Hg,
                                              const int* __restrict__ csr,
                                              const float* __restrict__ isd,
                                              const int* __restrict__ offsets,
                                              const int* __restrict__ deg,
                                              const float* __restrict__ b1,
                                              unsigned* __restrict__ H1g, int N) {
    int g = (int)(blockIdx.x & 7);
    int nblk = (int)(blockIdx.x >> 3);
    int wave = __builtin_amdgcn_readfirstlane(threadIdx.x >> 6);
    int lane = threadIdx.x & 63;
    int es = lane >> 3;                       // edge sub
    int p = lane & 7;                         // chpair
    const unsigned* hg = Hg + (size_t)g * ((size_t)(N + 1) * 8);
    float b1a = b1[g * 16 + 2 * p];
    float b1b = b1[g * 16 + 2 * p + 1];
    int node0 = nblk * 16 + wave * 4;         // N % 16 == 0, always in range
    #pragma unroll
    for (int k = 0; k < 4; ++k) {
        int node = node0 + k;
        int start = offsets[node];            // scalar
        int nb = (deg[node] + 15) >> 4;
        float isdn = isd[node];
        float a0 = 0.f, a1 = 0.f;
        for (int ib = 0; ib < nb; ++ib) {
            int b0 = start + ib * 16;
            int s0 = csr[b0 + es];
            int s1 = csr[b0 + 8 + es];
            unsigned q0 = hg[(size_t)s0 * 8 + p];
            unsigned q1 = hg[(size_t)s1 * 8 + p];
            a0 += bflo(q0) + bflo(q1);
            a1 += bfhi(q0) + bfhi(q1);
        }
        a0 += __shfl_xor(a0, 8);  a1 += __shfl_xor(a1, 8);
        a0 += __shfl_xor(a0, 16); a1 += __shfl_xor(a1, 16);
        a0 += __shfl_xor(a0, 32); a1 += __shfl_xor(a1, 32);
        if (es == 0) {
            float r0 = fmaxf(fmaf(isdn, a0, b1a), 0.f);
            float r1 = fmaxf(fmaf(isdn, a1, b1b), 0.f);
            H1g[(size_t)g * ((size_t)N * 8) + (size_t)node * 8 + p] =
                (unsigned)f2bf(r0) | ((unsigned)f2bf(r1) << 16);
        }
    }
}

// ---------------- GEMM2: h2'[N+1,40](bf16) = isd*(h1 @ W2), h1 group-major ----------
__global__ __launch_bounds__(256) void k_gemm2(const unsigned* __restrict__ H1g,
                                               const float* __restrict__ W2,
                                               const float* __restrict__ isd,
                                               unsigned short* __restrict__ H2, int N) {
    __shared__ float sH[64][132];
    __shared__ float sW[128 * 40];
    int tid = threadIdx.x;
    int block_row = blockIdx.x * 64;
    for (int i = tid; i < 64 * 64; i += 256) {     // uints
        int row = i >> 6;
        int u = i & 63;
        int g = u >> 3;
        int p = u & 7;
        int grow = block_row + row;
        unsigned v = 0;
        if (grow < N) v = H1g[(size_t)g * ((size_t)N * 8) + (size_t)grow * 8 + p];
        float* d = &sH[row][2 * u];
        d[0] = bflo(v); d[1] = bfhi(v);
    }
    for (int i = tid; i < 1280; i += 256)
        *(float4*)&sW[i * 4] = *(const float4*)&W2[(size_t)i * 4];
    __syncthreads();

    int row = tid >> 2;
    int c0 = (tid & 3) * 10;
    float acc[10] = {};
    for (int k = 0; k < 128; ++k) {
        float hv = sH[row][k];
        #pragma unroll
        for (int j = 0; j < 5; ++j) {
            float2 wv = *(const float2*)&sW[k * 40 + c0 + 2 * j];
            acc[2 * j]     = fmaf(hv, wv.x, acc[2 * j]);
            acc[2 * j + 1] = fmaf(hv, wv.y, acc[2 * j + 1]);
        }
    }
    int grow = block_row + row;
    if (grow < N) {
        float scn = isd[grow];
        unsigned* o = (unsigned*)&H2[(size_t)grow * 40 + c0];
        #pragma unroll
        for (int j = 0; j < 5; ++j)
            o[j] = (unsigned)f2bf(acc[2 * j] * scn) |
                   ((unsigned)f2bf(acc[2 * j + 1] * scn) << 16);
    }
}

// ---------------- agg2: out = b2 + isdn * sum h2'[src] , C=40 ----------------
__global__ __launch_bounds__(256) void k_agg2(const unsigned* __restrict__ Hu2,
                                              const int* __restrict__ csr,
                                              const float* __restrict__ isd,
                                              const int* __restrict__ offsets,
                                              const int* __restrict__ deg,
                                              const float* __restrict__ b2,
                                              float* __restrict__ out, int N) {
    int node = __builtin_amdgcn_readfirstlane((blockIdx.x * blockDim.x + threadIdx.x) >> 6);
    int lane = threadIdx.x & 63;
    if (node >= N) return;
    int start = offsets[node];
    int nb = (deg[node] + 15) >> 4;
    float isdn = isd[node];
    int sub = lane >> 5;       // 0/1
    int c = lane & 31;         // active c<20; c in [20,32) reads slack
    float acc0 = 0.f, acc1 = 0.f;
    for (int ib = 0; ib < nb; ++ib) {
        int b0 = start + ib * 16;
        #pragma unroll
        for (int j = 0; j < 8; ++j) {
            int s = csr[b0 + (j << 1) + sub];
            unsigned q = Hu2[(size_t)s * 20 + c];
            acc0 += bflo(q);
            acc1 += bfhi(q);
        }
    }
    acc0 += __shfl(acc0, lane + 32);
    acc1 += __shfl(acc1, lane + 32);
    if (lane < 20)
        *(float2*)&out[(size_t)node * 40 + 2 * lane] =
            make_float2(fmaf(isdn, acc0, b2[2 * lane]), fmaf(isdn, acc1, b2[2 * lane + 1]));
}

extern "C" void kernel_launch(void* const* d_in, const int* in_sizes, int n_in,
                              void* d_out, int out_size, void* d_ws, size_t ws_size,
                              hipStream_t stream) {
    const float* x  = (const float*)d_in[0];
    const int*  src = (const int*)d_in[1];
    const int*  dst = (const int*)d_in[2];
    const float* W1 = (const float*)d_in[3];
    const float* b1 = (const float*)d_in[4];
    const float* W2 = (const float*)d_in[5];
    const float* b2 = (const float*)d_in[6];
    float* out = (float*)d_out;

    const int N = in_sizes[0] / 256;   // 100000
    const int E = in_sizes[1];         // 1600000

    char* w = (char*)d_ws;
    auto alloc = [&](size_t bytes) -> void* {
        void* p = (void*)w;
        w += (bytes + 15) & ~(size_t)15;
        return p;
    };
    int*      gcursor = (int*)alloc(256 * 4);                 // zeroed
    int*      counter = (int*)alloc(16);                      // zeroed
    int*      deg     = (int*)alloc((size_t)N * 4);
    float*    isd     = (float*)alloc((size_t)(N + 1) * 4);
    int*      offsets = (int*)alloc((size_t)(N + 1) * 4);
    unsigned* buckets = (unsigned*)alloc((size_t)NBUCK * BBCAP * 4);
    int*      csr     = (int*)alloc((size_t)(E + 16 * (size_t)N) * 4);
    unsigned short* w1s = (unsigned short*)alloc(32768 * 2);
    unsigned* hg  = (unsigned*)alloc((size_t)8 * (N + 1) * 8 * 4);   // Hg group-major
    unsigned* h1g = (unsigned*)alloc((size_t)8 * N * 8 * 4);         // H1g group-major
    unsigned short* h2 = (unsigned short*)alloc(((size_t)(N + 1) * 20 + 16) * 4);

    hipMemsetAsync(gcursor, 0, 256 * 4 + 16, stream);

    int nchunk = (E + CHUNK - 1) / CHUNK;   // 392
    k_part<<<nchunk, 256, 0, stream>>>(src, dst, gcursor, buckets, E);
    k_count<<<NBUCK, 256, 0, stream>>>(buckets, gcursor, deg, N);
    k_isd_offsets<<<(N + 256) / 256, 256, 0, stream>>>(deg, isd, offsets, counter, N);
    k_place<<<NBUCK, 256, 0, stream>>>(buckets, gcursor, offsets, deg, csr, N);
    k_prep_w1<<<16, 256, 0, stream>>>(W1, w1s, (unsigned*)h2 + (size_t)N * 20);
    k_gemm1<<<(N + 63) / 64, 256, 0, stream>>>(x, w1s, isd, hg, N);
    k_agg1<<<8 * (N / 16), 256, 0, stream>>>(hg, csr, isd, offsets, deg, b1, h1g, N);
    k_gemm2<<<(N + 63) / 64, 256, 0, stream>>>(h1g, W2, isd, h2, N);
    k_agg2<<<(N + 3) / 4, 256, 0, stream>>>((const unsigned*)h2, csr, isd, offsets, deg,
                                            b2, out, N);
}